// Round 3
// baseline (780.684 us; speedup 1.0000x reference)
//
#include <hip/hip_runtime.h>

#define SEQ_LEN 300
#define ROW_STRIDE 302   // 300 rates + market_price + bid
#define ROWS_PER_BLOCK 16

// One 64-lane wave per row, interleaved coalesced layout:
//   slot s (0..2), lane l owns elements 128s + 2l and 128s + 2l + 1 (float2).
// Loads are predicated on kmax = max(bid, mp+1): element indices >= kmax are
// never used, and they form a contiguous address tail per row, so the
// predication skips whole cache lines (~28% of read traffic on average).
// rates[mp] is recovered from registers via one __shfl (mp < kmax always),
// so there is no dependent scalar re-load.
// 16 waves per block handle 16 consecutive rows; results are staged in LDS
// and written as two 64-byte contiguous chunks (no scattered dword stores).
__global__ __launch_bounds__(1024) void bidprefix_kernel(
    const float* __restrict__ in, float* __restrict__ out, int batch) {
  const int lane = threadIdx.x & 63;
  const int wave = threadIdx.x >> 6;                  // 0..15
  const int row = blockIdx.x * ROWS_PER_BLOCK + wave;

  __shared__ float s_out[2][ROWS_PER_BLOCK];

  float pb = 1.0f, pm = 1.0f, rmp = 0.0f;
  if (row < batch) {
    const float* __restrict__ rp = in + (long long)row * ROW_STRIDE;

    // Indices first (broadcast 8B load; row base is 8B-aligned: 1208=151*8).
    const float2 idxpair = *(const float2*)(rp + SEQ_LEN);
    const int mp  = (int)idxpair.x;        // [0, 299]
    const int bid = (int)idxpair.y;        // [0, 300]
    const int kmax = max(bid, mp + 1);     // [1, 300]

    const int l2 = 2 * lane;

    // Predicated coalesced float2 loads; off lanes keep identity.
    // (kmax <= 300 makes l2 < kmax-256 imply lane <= 21, i.e. addr <= 298.)
    float2 v0 = make_float2(1.0f, 1.0f);
    float2 v1 = make_float2(1.0f, 1.0f);
    float2 v2 = make_float2(1.0f, 1.0f);
    if (l2 < kmax)       v0 = *(const float2*)(rp + l2);
    if (l2 < kmax - 128) v1 = *(const float2*)(rp + 128 + l2);
    if (l2 < kmax - 256) v2 = *(const float2*)(rp + 256 + l2);

    // Partial products under the two thresholds (idx < bid, idx < mp).
    float e;
    e = (l2 < bid      ) ? v0.x : 1.0f;  pb *= e;
    e = (l2 < bid - 1  ) ? v0.y : 1.0f;  pb *= e;
    e = (l2 < bid - 128) ? v1.x : 1.0f;  pb *= e;
    e = (l2 < bid - 129) ? v1.y : 1.0f;  pb *= e;
    e = (l2 < bid - 256) ? v2.x : 1.0f;  pb *= e;
    e = (l2 < bid - 257) ? v2.y : 1.0f;  pb *= e;

    e = (l2 < mp       ) ? v0.x : 1.0f;  pm *= e;
    e = (l2 < mp - 1   ) ? v0.y : 1.0f;  pm *= e;
    e = (l2 < mp - 128 ) ? v1.x : 1.0f;  pm *= e;
    e = (l2 < mp - 129 ) ? v1.y : 1.0f;  pm *= e;
    e = (l2 < mp - 256 ) ? v2.x : 1.0f;  pm *= e;
    e = (l2 < mp - 257 ) ? v2.y : 1.0f;  pm *= e;

    // rates[mp] from registers: mp = 128s + 2*srclane + c, all wave-uniform.
    const int s = mp >> 7;
    const int c = mp & 1;
    const int srclane = (mp & 127) >> 1;
    const float val = (s == 0) ? (c ? v0.y : v0.x)
                    : (s == 1) ? (c ? v1.y : v1.x)
                               : (c ? v2.y : v2.x);
    rmp = __shfl(val, srclane, 64);

    // Two independent butterfly product-reductions (2-way ILP).
#pragma unroll
    for (int d = 1; d < 64; d <<= 1) {
      pb *= __shfl_xor(pb, d, 64);
      pm *= __shfl_xor(pm, d, 64);
    }
  }

  if (lane == 0) {
    s_out[0][wave] = pb;                  // survival_rate = cp1[bid]
    s_out[1][wave] = pm * (1.0f - rmp);   // cp1[mp] - cp1[mp+1]
  }
  __syncthreads();

  // Coalesced 64B-contiguous output stores (one wave does both chunks).
  const int t = threadIdx.x;
  if (t < ROWS_PER_BLOCK) {
    const int r = blockIdx.x * ROWS_PER_BLOCK + t;
    if (r < batch) out[r] = s_out[0][t];
  } else if (t >= 32 && t < 32 + ROWS_PER_BLOCK) {
    const int r = blockIdx.x * ROWS_PER_BLOCK + (t - 32);
    if (r < batch) out[batch + r] = s_out[1][t - 32];
  }
}

extern "C" void kernel_launch(void* const* d_in, const int* in_sizes, int n_in,
                              void* d_out, int out_size, void* d_ws, size_t ws_size,
                              hipStream_t stream) {
  (void)n_in; (void)d_ws; (void)ws_size; (void)out_size;
  const float* in = (const float*)d_in[0];
  float* out = (float*)d_out;
  const int batch = in_sizes[0] / ROW_STRIDE;   // 500000
  const int grid = (batch + ROWS_PER_BLOCK - 1) / ROWS_PER_BLOCK;
  bidprefix_kernel<<<grid, 1024, 0, stream>>>(in, out, batch);
}